// Round 8
// baseline (382.722 us; speedup 1.0000x reference)
//
#include <hip/hip_runtime.h>

#define NN 50000
#define NE 400000
#define NBINS 1024
#define NSBIN 512

// weight offsets (layout from convert_weights)
#define RL1ST 0            // l1s transposed: (192,64), col-contiguous
#define RL1VT 12288        // l1v transposed: (64,64)
#define RL2S  16384        // l2s original (160,32)
#define RL2V  21504        // l2v original (96,32)
#define WTOT  24576

#define SLUT_N ((NBINS+1)*256)        // 262400
// ints: offs NN+1 | curs NN | eids NE | sorted/cnt NN | hist 512 | bsum 256 | bbase 256
#define INTS_N (3*NN + 1 + NE + 1024) // 551025
#define FIXED_FL ((size_t)WTOT + SLUT_N + INTS_N)   // 838001

#define SCAN_B 196                    // ceil(NN/256)

#define S160 0.07905694150420949f
#define S96  0.10206207261596576f

__device__ __forceinline__ float sigf(float x){
  return __builtin_amdgcn_rcpf(1.0f + __expf(-x));
}
__device__ __forceinline__ float siluf(float x){ return x * sigf(x); }

// ---- weights: transpose l1s,l1v; copy l2s,l2v ----
__global__ __launch_bounds__(256) void convert_weights(
    const float* __restrict__ l1s, const float* __restrict__ l1v,
    const float* __restrict__ l2s, const float* __restrict__ l2v,
    float* __restrict__ wgt)
{
  int i = blockIdx.x*256 + threadIdx.x;
  if (i < 12288){ int o=i>>6, m=i&63; wgt[RL1ST + i] = l1s[m*192+o]; return; }
  if (i < 16384){ int t=i-12288; int o=t>>6, m=t&63; wgt[RL1VT + t] = l1v[m*64+o]; return; }
  if (i < 21504){ int t=i-16384; wgt[RL2S + t] = l2s[t]; return; }
  if (i < 24576){ int t=i-21504; wgt[RL2V + t] = l2v[t]; return; }
}

// ---- SLUT[bin][256]: scal(x) at bin edges, per-lane-slot order (c=m*8+q) ----
__global__ __launch_bounds__(128) void build_lut(
    const float* __restrict__ w1, const float* __restrict__ b1,
    const float* __restrict__ w2, const float* __restrict__ b2,
    const float* __restrict__ w3, const float* __restrict__ b3,
    float* __restrict__ slut)
{
  __shared__ float h1[64], h2[64], scal[128];
  int bin = blockIdx.x;            // 0..NBINS
  float x = (float)bin / (float)NBINS;
  int t = threadIdx.x;
  if (t < 64) h1[t] = siluf(fmaf(x, w1[t], b1[t]));
  __syncthreads();
  if (t < 64){
    float a = b2[t];
    for (int k=0;k<64;k++) a = fmaf(h1[k], w2[k*64+t], a);
    h2[t] = siluf(a);
  }
  __syncthreads();
  {
    float a = b3[t];
    for (int k=0;k<64;k++) a = fmaf(h2[k], w3[k*128+t], a);
    scal[t] = a;
  }
  __syncthreads();
  for (int c=t; c<256; c+=128){
    int m=c>>3, q=c&7;
    int idx = (q==0)? m : (q==1)? (32+m) : (q<5)? (64+m) : (96+m);
    slut[(size_t)bin*256 + c] = scal[idx];
  }
}

// ================= CSR build =================
__global__ __launch_bounds__(256) void count_kernel(
    const int* __restrict__ rcv, int* __restrict__ cnt)
{
  int e = blockIdx.x*256 + threadIdx.x;
  if (e < NE) atomicAdd(&cnt[rcv[e]], 1);
}

__global__ __launch_bounds__(256) void scan_a(
    const int* __restrict__ cnt, int* __restrict__ offs, int* __restrict__ bsum)
{
  __shared__ int sd[256];
  int tid = threadIdx.x;
  int i = blockIdx.x*256 + tid;
  int c = (i < NN) ? cnt[i] : 0;
  sd[tid] = c;
  __syncthreads();
  for (int off=1; off<256; off<<=1){
    int t = (tid >= off) ? sd[tid-off] : 0;
    __syncthreads();
    sd[tid] += t;
    __syncthreads();
  }
  if (i < NN) offs[i] = sd[tid] - c;          // local exclusive
  if (tid == 255) bsum[blockIdx.x] = sd[255]; // block total
}

__global__ __launch_bounds__(256) void scan_b(
    const int* __restrict__ bsum, int* __restrict__ bbase, int* __restrict__ offs)
{
  __shared__ int sd[256];
  int tid = threadIdx.x;
  int v = (tid < SCAN_B) ? bsum[tid] : 0;
  sd[tid] = v;
  __syncthreads();
  for (int off=1; off<256; off<<=1){
    int t = (tid >= off) ? sd[tid-off] : 0;
    __syncthreads();
    sd[tid] += t;
    __syncthreads();
  }
  if (tid < SCAN_B) bbase[tid] = sd[tid] - v;
  if (tid == 255) offs[NN] = sd[255];
}

__global__ __launch_bounds__(256) void scan_c(
    const int* __restrict__ bbase, int* __restrict__ offs, int* __restrict__ curs)
{
  int i = blockIdx.x*256 + threadIdx.x;
  if (i < NN){
    int o = offs[i] + bbase[blockIdx.x];
    offs[i] = o;
    curs[i] = o;
  }
}

__global__ __launch_bounds__(256) void scatter_kernel(
    const int* __restrict__ rcv, int* __restrict__ curs, int* __restrict__ eids)
{
  int e = blockIdx.x*256 + threadIdx.x;
  if (e >= NE) return;
  int pos = atomicAdd(&curs[rcv[e]], 1);
  eids[pos] = e;
}

// ====== degree sort (per chunk), LDS-privatized counting sort ==============
// bin = NSBIN-1-min(d,NSBIN-1) => descending degree order
__global__ __launch_bounds__(256) void dhist_kernel(
    const int* __restrict__ offs, int* __restrict__ hist, int cn0, int cnn)
{
  __shared__ int lh[NSBIN];
  for (int j=threadIdx.x; j<NSBIN; j+=256) lh[j]=0;
  __syncthreads();
  int i = blockIdx.x*256 + threadIdx.x;
  if (i < cnn){
    int n = cn0 + i;
    int d = offs[n+1] - offs[n];
    int b = (d < NSBIN) ? (NSBIN-1-d) : 0;
    atomicAdd(&lh[b], 1);
  }
  __syncthreads();
  for (int j=threadIdx.x; j<NSBIN; j+=256){
    int v = lh[j];
    if (v) atomicAdd(&hist[j], v);
  }
}

__global__ __launch_bounds__(512) void dhist_scan(int* __restrict__ hist)
{
  __shared__ int sd[512];
  int t = threadIdx.x;
  int v = hist[t];
  sd[t] = v;
  __syncthreads();
  for (int off=1; off<512; off<<=1){
    int x = (t >= off) ? sd[t-off] : 0;
    __syncthreads();
    sd[t] += x;
    __syncthreads();
  }
  hist[t] = sd[t] - v;   // exclusive prefix -> global cursor
}

// per-block: LDS rank within (block,bin); ONE global atomic per (block,bin)
__global__ __launch_bounds__(256) void dsort_kernel(
    const int* __restrict__ offs, int* __restrict__ hist,
    int* __restrict__ sorted, int cn0, int cnn)
{
  __shared__ int lh[NSBIN];   // local counts
  __shared__ int lb[NSBIN];   // block base per bin
  for (int j=threadIdx.x; j<NSBIN; j+=256) lh[j]=0;
  __syncthreads();
  int i = blockIdx.x*256 + threadIdx.x;
  int b = -1, rank = 0;
  if (i < cnn){
    int n = cn0 + i;
    int d = offs[n+1] - offs[n];
    b = (d < NSBIN) ? (NSBIN-1-d) : 0;
    rank = atomicAdd(&lh[b], 1);
  }
  __syncthreads();
  for (int j=threadIdx.x; j<NSBIN; j+=256){
    int v = lh[j];
    lb[j] = v ? atomicAdd(&hist[j], v) : 0;
  }
  __syncthreads();
  if (i < cnn) sorted[cn0 + lb[b] + rank] = cn0 + i;
}

// ================= Edge+aggregate: wave per node (degree-sorted) ===========
// Output layout: agg[n-cn0][c'] with c' = block*32 + m.
// Depth-2 gather pipeline: compute(p) || G-in-flight(p+1) || G-issue(p+2),
// meta runs 3 ahead. All indices clamped to plast (dup loads are L1 hits).
__global__ __launch_bounds__(256) void edge_agg_kernel(
    const float* __restrict__ ns, const float* __restrict__ nv,
    const float* __restrict__ sh, const float* __restrict__ nrm,
    const int* __restrict__ snd,
    const int* __restrict__ offs, const int* __restrict__ eids,
    const int* __restrict__ sorted,
    const float* __restrict__ slut,
    float* __restrict__ agg, int cn0, int cnn)
{
  int wave = threadIdx.x >> 6;
  int lane = threadIdx.x & 63;
  int nls = blockIdx.x*4 + wave;
  if (nls >= cnn) return;
  int n = sorted[cn0 + nls];
  int m = lane >> 1;
  int odd = lane & 1;
  int p0 = offs[n], p1 = offs[n+1];
  const float4* slut4 = (const float4*)slut;
  const float inv_sqrt3 = 0.57735026918962576f;
  float a0=0.f, a1=0.f, a2=0.f, a3=0.f;

  if (p0 < p1){
    const int plast = p1 - 1;

#define LDM(P, S, X, Y) { int _e = eids[(P)]; S = snd[_e]; X = nrm[_e]; \
                          Y = *(const float4*)(sh + 4*_e); }
#define GLOAD(S, X, Y, Gtt, GLa, GLb, Gse, Gw, Gv2, Gy) { \
    float _f = fminf(fmaxf((X)*(float)NBINS, 0.0f), (float)NBINS - 0.001f); \
    int _b = (int)_f; Gtt = _f - (float)_b; \
    GLa = slut4[(size_t)_b*64 + lane]; \
    GLb = slut4[(size_t)(_b+1)*64 + lane]; \
    Gse = ns[(size_t)(S)*32 + m]; \
    Gw  = *(const float2*)(nv + (size_t)(S)*96 + 3*m); \
    Gv2 = nv[(size_t)(S)*96 + 3*m + 2]; \
    Gy = Y; }

    int sA, sB, sC;  float xA, xB, xC;  float4 yA, yB, yC;
    LDM(p0, sA, xA, yA);
    { int pm = (p0+1 <= plast) ? (p0+1) : plast; LDM(pm, sB, xB, yB); }
    { int pm = (p0+2 <= plast) ? (p0+2) : plast; LDM(pm, sC, xC, yC); }

    float tt0; float4 La0, Lb0; float se0; float2 w0; float vv0; float4 y0;
    float tt1; float4 La1, Lb1; float se1; float2 w1; float vv1; float4 y1;
    GLOAD(sA, xA, yA, tt0, La0, Lb0, se0, w0, vv0, y0);
    GLOAD(sB, xB, yB, tt1, La1, Lb1, se1, w1, vv1, y1);

    for (int p = p0; p <= plast; ++p){
      // meta(p+3)
      int sD; float xD; float4 yD;
      { int pm = (p+3 <= plast) ? (p+3) : plast; LDM(pm, sD, xD, yD); }
      // issue G(p+2)
      float tt2; float4 La2, Lb2; float se2; float2 w2; float vv2; float4 y2;
      GLOAD(sC, xC, yC, tt2, La2, Lb2, se2, w2, vv2, y2);

      // compute C(p) from stage-0 (issued two iterations ago)
      float sc0 = fmaf(tt0, Lb0.x-La0.x, La0.x);
      float sc1 = fmaf(tt0, Lb0.y-La0.y, La0.y);
      float sc2 = fmaf(tt0, Lb0.z-La0.z, La0.z);
      float sc3 = fmaf(tt0, Lb0.w-La0.w, La0.w);
      float A0,A1,A2,A3;
      if (!odd){
        float dot = fmaf(y0.w, vv0, fmaf(y0.z, w0.y, y0.y*w0.x));
        A0 = y0.x*se0; A1 = dot*inv_sqrt3; A2 = y0.x*w0.x; A3 = y0.x*w0.y;
      } else {
        A0 = y0.x*vv0; A1 = y0.y*se0; A2 = y0.z*se0; A3 = y0.w*se0;
      }
      a0 = fmaf(A0, sc0, a0);
      a1 = fmaf(A1, sc1, a1);
      a2 = fmaf(A2, sc2, a2);
      a3 = fmaf(A3, sc3, a3);

      // rotate pipeline
      tt0=tt1; La0=La1; Lb0=Lb1; se0=se1; w0=w1; vv0=vv1; y0=y1;
      tt1=tt2; La1=La2; Lb1=Lb2; se1=se2; w1=w2; vv1=vv2; y1=y2;
      sC=sD; xC=xD; yC=yD;
    }
#undef LDM
#undef GLOAD
  }
  int deg = p1 - p0;
  float inv = (deg > 0) ? __builtin_amdgcn_rcpf((float)deg) : 1.0f;
  float* ap = agg + (size_t)(n - cn0)*256;
  int pos0 = odd ? (192+m) : m;        // q4 : q0
  int pos1 = odd ? ( 96+m) : (32+m);   // q5 : q1
  int pos2 = odd ? (160+m) : (64+m);   // q6 : q2
  int pos3 = odd ? (224+m) : (128+m);  // q7 : q3
  ap[pos0] = a0*inv;
  ap[pos1] = a1*inv;
  ap[pos2] = a2*inv;
  ap[pos3] = a3*inv;
}

// ================= Node phase: no weight staging, contiguous agg slices ====
__global__ __launch_bounds__(256) __attribute__((amdgpu_waves_per_eu(3,8)))
void node_s_kernel(
    const float* __restrict__ ns, const float* __restrict__ wgt,
    const float* __restrict__ agg, int cn0, int cnn,
    float* __restrict__ out)
{
  __shared__ float red[3*64*33];     // 25.3 KB
  int lane = threadIdx.x & 63, role = threadIdx.x >> 6;
  int ro = __builtin_amdgcn_readfirstlane(role);
  int nl = blockIdx.x*64 + lane;
  bool valid = (nl < cnn);
  int nls = valid ? nl : (cnn-1);
  int n = cn0 + nl;

  float aggs[64];
  float oacc[32];
  #pragma unroll
  for (int j=0;j<32;j++) oacc[j]=0.0f;

  {
    const float4* ar = (const float4*)(agg + (size_t)nls*256);
    #pragma unroll
    for (int g=0; g<16; g++){
      float4 v = ar[g];
      aggs[4*g+0]=v.x; aggs[4*g+1]=v.y; aggs[4*g+2]=v.z; aggs[4*g+3]=v.w;
    }
  }
  const float* l1sT = wgt + RL1ST + ro*32*64;
  const float* l2s  = wgt + RL2S;
  for (int t=0;t<32;t++){
    const float4* col = (const float4*)(l1sT + t*64);
    float d0=0,d1=0,d2=0,d3=0;
    #pragma unroll
    for (int j=0;j<16;j++){
      float4 c = col[j];
      d0 = fmaf(aggs[4*j+0], c.x, d0);
      d1 = fmaf(aggs[4*j+1], c.y, d1);
      d2 = fmaf(aggs[4*j+2], c.z, d2);
      d3 = fmaf(aggs[4*j+3], c.w, d3);
    }
    float act = siluf(((d0+d1)+(d2+d3))*0.125f);
    const float4* row = (const float4*)(l2s + (size_t)(ro*32 + t)*32);
    #pragma unroll
    for (int j=0;j<8;j++){
      float4 w = row[j];
      oacc[4*j+0] = fmaf(act, w.x, oacc[4*j+0]);
      oacc[4*j+1] = fmaf(act, w.y, oacc[4*j+1]);
      oacc[4*j+2] = fmaf(act, w.z, oacc[4*j+2]);
      oacc[4*j+3] = fmaf(act, w.w, oacc[4*j+3]);
    }
  }
  {
    const float4* sp = (const float4*)(ns + (size_t)(cn0+nls)*32 + ro*8);
    #pragma unroll
    for (int q4=0;q4<2;q4++){
      float4 v = sp[q4];
      float vv[4] = {v.x, v.y, v.z, v.w};
      #pragma unroll
      for (int u=0;u<4;u++){
        int q = ro*8 + q4*4 + u;
        const float4* row = (const float4*)(l2s + (size_t)(128+q)*32);
        #pragma unroll
        for (int j=0;j<8;j++){
          float4 w = row[j];
          oacc[4*j+0] = fmaf(vv[u], w.x, oacc[4*j+0]);
          oacc[4*j+1] = fmaf(vv[u], w.y, oacc[4*j+1]);
          oacc[4*j+2] = fmaf(vv[u], w.z, oacc[4*j+2]);
          oacc[4*j+3] = fmaf(vv[u], w.w, oacc[4*j+3]);
        }
      }
    }
  }

  if (role != 0){
    float* rp = red + (role-1)*(64*33) + lane*33;
    #pragma unroll
    for (int j=0;j<32;j++) rp[j] = oacc[j];
  }
  __syncthreads();
  if (role == 0 && valid){
    #pragma unroll
    for (int j=0;j<32;j++)
      oacc[j] += red[0*(64*33)+lane*33+j] + red[1*(64*33)+lane*33+j]
               + red[2*(64*33)+lane*33+j];
    float4* op = (float4*)(out + (size_t)n*128);
    #pragma unroll
    for (int j=0;j<8;j++){
      float4 o4;
      o4.x = oacc[4*j+0]*S160; o4.y = oacc[4*j+1]*S160;
      o4.z = oacc[4*j+2]*S160; o4.w = oacc[4*j+3]*S160;
      op[j] = o4;
    }
  }
}

__global__ __launch_bounds__(192) __attribute__((amdgpu_waves_per_eu(3,8)))
void node_v_kernel(
    const float* __restrict__ nv, const float* __restrict__ wgt,
    const float* __restrict__ agg, int cn0, int cnn,
    float* __restrict__ out)
{
  __shared__ float sw[64*97];        // 24.8 KB (sgate uses first 4096 floats)
  int lane = threadIdx.x & 63, role = threadIdx.x >> 6;  // role 0..2
  int ro = __builtin_amdgcn_readfirstlane(role);
  int nl = blockIdx.x*64 + lane;
  bool valid = (nl < cnn);
  int nls = valid ? nl : (cnn-1);
  const float* arow = agg + (size_t)nls*256;

  // ---- Phase A: gates ----
  {
    float aggs[64];
    const float4* ar = (const float4*)arow;
    #pragma unroll
    for (int g=0; g<16; g++){
      float4 v = ar[g];
      aggs[4*g+0]=v.x; aggs[4*g+1]=v.y; aggs[4*g+2]=v.z; aggs[4*g+3]=v.w;
    }
    const float* l1g = wgt + RL1ST + 128*64;     // gate cols 128..191
    for (int o=ro; o<64; o+=3){
      const float4* col = (const float4*)(l1g + o*64);
      float d0=0,d1=0,d2=0,d3=0;
      #pragma unroll
      for (int j=0;j<16;j++){
        float4 c = col[j];
        d0 = fmaf(aggs[4*j+0], c.x, d0);
        d1 = fmaf(aggs[4*j+1], c.y, d1);
        d2 = fmaf(aggs[4*j+2], c.z, d2);
        d3 = fmaf(aggs[4*j+3], c.w, d3);
      }
      sw[o*64+lane] = sigf(((d0+d1)+(d2+d3))*0.125f);
    }
  }
  __syncthreads();

  // ---- Phase B: component k = role ----
  int k = role;
  float aggv[64], oacc[32];
  #pragma unroll
  for (int j=0;j<32;j++) oacc[j]=0.0f;
  {
    const float4* av = (const float4*)(arow + 64 + 64*k);
    #pragma unroll
    for (int g=0; g<16; g++){
      float4 v = av[g];
      aggv[4*g+0]=v.x; aggv[4*g+1]=v.y; aggv[4*g+2]=v.z; aggv[4*g+3]=v.w;
    }
  }
  const float* l1vT = wgt + RL1VT;
  const float* l2v  = wgt + RL2V;
  for (int o=0;o<64;o++){
    const float4* col = (const float4*)(l1vT + o*64);
    float d0=0,d1=0,d2=0,d3=0;
    #pragma unroll
    for (int j=0;j<16;j++){
      float4 c = col[j];
      d0 = fmaf(aggv[4*j+0], c.x, d0);
      d1 = fmaf(aggv[4*j+1], c.y, d1);
      d2 = fmaf(aggv[4*j+2], c.z, d2);
      d3 = fmaf(aggv[4*j+3], c.w, d3);
    }
    float gv = (((d0+d1)+(d2+d3))*0.125f) * sw[o*64+lane];
    const float4* row = (const float4*)(l2v + (size_t)o*32);
    #pragma unroll
    for (int j=0;j<8;j++){
      float4 w = row[j];
      oacc[4*j+0] = fmaf(gv, w.x, oacc[4*j+0]);
      oacc[4*j+1] = fmaf(gv, w.y, oacc[4*j+1]);
      oacc[4*j+2] = fmaf(gv, w.z, oacc[4*j+2]);
      oacc[4*j+3] = fmaf(gv, w.w, oacc[4*j+3]);
    }
  }
  {
    const float* vp = nv + (size_t)(cn0+nls)*96 + k;
    #pragma unroll 8
    for (int q=0;q<32;q++){
      float a = vp[3*q];
      const float4* row = (const float4*)(l2v + (size_t)(64+q)*32);
      #pragma unroll
      for (int j=0;j<8;j++){
        float4 w = row[j];
        oacc[4*j+0] = fmaf(a, w.x, oacc[4*j+0]);
        oacc[4*j+1] = fmaf(a, w.y, oacc[4*j+1]);
        oacc[4*j+2] = fmaf(a, w.z, oacc[4*j+2]);
        oacc[4*j+3] = fmaf(a, w.w, oacc[4*j+3]);
      }
    }
  }

  __syncthreads();          // done reading sgate region
  if (valid){
    #pragma unroll
    for (int j=0;j<32;j++) sw[lane*97 + 3*j + k] = oacc[j]*S96;
  }
  __syncthreads();
  int nb = blockIdx.x*64;
  #pragma unroll
  for (int r=0;r<8;r++){
    int F = r*192 + threadIdx.x;       // 0..1535 -> 64 nodes x 24 float4
    int i = F/24, j = F%24;
    if (nb + i < cnn){
      float4 o4;
      o4.x = sw[i*97 + 4*j + 0];
      o4.y = sw[i*97 + 4*j + 1];
      o4.z = sw[i*97 + 4*j + 2];
      o4.w = sw[i*97 + 4*j + 3];
      *(float4*)(out + (size_t)(cn0+nb+i)*128 + 32 + 4*j) = o4;
    }
  }
}

extern "C" void kernel_launch(void* const* d_in, const int* in_sizes, int n_in,
                              void* d_out, int out_size, void* d_ws, size_t ws_size,
                              hipStream_t stream) {
  const float* node_scalars = (const float*)d_in[0];
  const float* node_vectors = (const float*)d_in[1];
  const float* sh           = (const float*)d_in[2];
  const float* norm         = (const float*)d_in[3];
  const float* w1  = (const float*)d_in[4];
  const float* b1  = (const float*)d_in[5];
  const float* w2  = (const float*)d_in[6];
  const float* b2  = (const float*)d_in[7];
  const float* w3  = (const float*)d_in[8];
  const float* b3  = (const float*)d_in[9];
  const float* l1s = (const float*)d_in[10];
  const float* l1v = (const float*)d_in[11];
  const float* l2s = (const float*)d_in[12];
  const float* l2v = (const float*)d_in[13];
  const int* snd = (const int*)d_in[14];
  const int* rcv = (const int*)d_in[15];
  float* ws = (float*)d_ws;
  float* out = (float*)d_out;

  // layout: wgt | slut | ints | agg(remainder)
  size_t ws_fl = ws_size / 4;
  if (ws_fl < FIXED_FL + 64*256) return;
  size_t aggcap = (ws_fl - FIXED_FL) / 256;
  int csize = (int)((aggcap < (size_t)NN) ? aggcap : (size_t)NN);
  int nchunks = (NN + csize - 1) / csize;

  float* wgt  = ws;
  float* slut = wgt + WTOT;
  int*   ib   = (int*)(slut + SLUT_N);
  int* offs   = ib;                     // NN+1
  int* curs   = ib + NN + 1;            // NN
  int* eids   = ib + 2*NN + 1;          // NE
  int* sorted = ib + 2*NN + 1 + NE;     // NN (aliases cnt)
  int* cnt    = sorted;
  int* hist   = ib + 3*NN + 1 + NE;     // 512
  int* bsum   = hist + 512;             // 256
  int* bbase  = bsum + 256;             // 256
  float* agg  = (float*)(bbase + 256);

  hipMemsetAsync(cnt, 0, NN*sizeof(int), stream);

  convert_weights<<<(WTOT+255)/256, 256, 0, stream>>>(l1s, l1v, l2s, l2v, wgt);
  build_lut<<<NBINS+1, 128, 0, stream>>>(w1,b1,w2,b2,w3,b3, slut);

  count_kernel<<<(NE+255)/256, 256, 0, stream>>>(rcv, cnt);
  scan_a<<<SCAN_B, 256, 0, stream>>>(cnt, offs, bsum);
  scan_b<<<1, 256, 0, stream>>>(bsum, bbase, offs);
  scan_c<<<SCAN_B, 256, 0, stream>>>(bbase, offs, curs);
  scatter_kernel<<<(NE+255)/256, 256, 0, stream>>>(rcv, curs, eids);

  for (int ch = 0; ch < nchunks; ch++){
    int cn0 = ch * csize;
    int cnn = (NN - cn0 < csize) ? (NN - cn0) : csize;
    // degree-sort this chunk's nodes (descending) for balanced waves
    hipMemsetAsync(hist, 0, NSBIN*sizeof(int), stream);
    dhist_kernel<<<(cnn+255)/256, 256, 0, stream>>>(offs, hist, cn0, cnn);
    dhist_scan<<<1, 512, 0, stream>>>(hist);
    dsort_kernel<<<(cnn+255)/256, 256, 0, stream>>>(offs, hist, sorted, cn0, cnn);

    edge_agg_kernel<<<(cnn+3)/4, 256, 0, stream>>>(
        node_scalars, node_vectors, sh, norm, snd, offs, eids, sorted, slut,
        agg, cn0, cnn);
    node_s_kernel<<<(cnn+63)/64, 256, 0, stream>>>(
        node_scalars, wgt, agg, cn0, cnn, out);
    node_v_kernel<<<(cnn+63)/64, 192, 0, stream>>>(
        node_vectors, wgt, agg, cn0, cnn, out);
  }
}

// Round 9
// 354.151 us; speedup vs baseline: 1.0807x; 1.0807x over previous
//
#include <hip/hip_runtime.h>

#define NN 50000
#define NE 400000
#define NBINS 1024
#define NSBIN 512

// weight offsets (layout from convert_weights)
#define RL1ST 0            // l1s transposed: (192,64), col-contiguous
#define RL1VT 12288        // l1v transposed: (64,64)
#define RL2S  16384        // l2s original (160,32)
#define RL2V  21504        // l2v original (96,32)
#define WTOT  24576

#define SLUT_N ((NBINS+1)*256)        // 262400
// ints: offs NN+1 | curs NN | eids NE | sorted/cnt NN | hist 512 | bsum 256 | bbase 256
#define INTS_N (3*NN + 1 + NE + 1024) // 551025
#define FIXED_FL ((size_t)WTOT + SLUT_N + INTS_N)   // 838001

#define SCAN_B 196                    // ceil(NN/256)

#define S160 0.07905694150420949f
#define S96  0.10206207261596576f

__device__ __forceinline__ float sigf(float x){
  return __builtin_amdgcn_rcpf(1.0f + __expf(-x));
}
__device__ __forceinline__ float siluf(float x){ return x * sigf(x); }

// ---- weights: transpose l1s,l1v; copy l2s,l2v ----
__global__ __launch_bounds__(256) void convert_weights(
    const float* __restrict__ l1s, const float* __restrict__ l1v,
    const float* __restrict__ l2s, const float* __restrict__ l2v,
    float* __restrict__ wgt)
{
  int i = blockIdx.x*256 + threadIdx.x;
  if (i < 12288){ int o=i>>6, m=i&63; wgt[RL1ST + i] = l1s[m*192+o]; return; }
  if (i < 16384){ int t=i-12288; int o=t>>6, m=t&63; wgt[RL1VT + t] = l1v[m*64+o]; return; }
  if (i < 21504){ int t=i-16384; wgt[RL2S + t] = l2s[t]; return; }
  if (i < 24576){ int t=i-21504; wgt[RL2V + t] = l2v[t]; return; }
}

// ---- SLUT[bin][256]: scal(x) at bin edges, per-lane-slot order (c=m*8+q) ----
// q==1 entries are pre-multiplied by 1/sqrt(3) (dot-term scale folded in).
__global__ __launch_bounds__(128) void build_lut(
    const float* __restrict__ w1, const float* __restrict__ b1,
    const float* __restrict__ w2, const float* __restrict__ b2,
    const float* __restrict__ w3, const float* __restrict__ b3,
    float* __restrict__ slut)
{
  __shared__ float h1[64], h2[64], scal[128];
  int bin = blockIdx.x;            // 0..NBINS
  float x = (float)bin / (float)NBINS;
  int t = threadIdx.x;
  if (t < 64) h1[t] = siluf(fmaf(x, w1[t], b1[t]));
  __syncthreads();
  if (t < 64){
    float a = b2[t];
    for (int k=0;k<64;k++) a = fmaf(h1[k], w2[k*64+t], a);
    h2[t] = siluf(a);
  }
  __syncthreads();
  {
    float a = b3[t];
    for (int k=0;k<64;k++) a = fmaf(h2[k], w3[k*128+t], a);
    scal[t] = a;
  }
  __syncthreads();
  for (int c=t; c<256; c+=128){
    int m=c>>3, q=c&7;
    int idx = (q==0)? m : (q==1)? (32+m) : (q<5)? (64+m) : (96+m);
    float v = scal[idx];
    if (q == 1) v *= 0.57735026918962576f;
    slut[(size_t)bin*256 + c] = v;
  }
}

// ================= CSR build =================
__global__ __launch_bounds__(256) void count_kernel(
    const int* __restrict__ rcv, int* __restrict__ cnt)
{
  int e = blockIdx.x*256 + threadIdx.x;
  if (e < NE) atomicAdd(&cnt[rcv[e]], 1);
}

__global__ __launch_bounds__(256) void scan_a(
    const int* __restrict__ cnt, int* __restrict__ offs, int* __restrict__ bsum)
{
  __shared__ int sd[256];
  int tid = threadIdx.x;
  int i = blockIdx.x*256 + tid;
  int c = (i < NN) ? cnt[i] : 0;
  sd[tid] = c;
  __syncthreads();
  for (int off=1; off<256; off<<=1){
    int t = (tid >= off) ? sd[tid-off] : 0;
    __syncthreads();
    sd[tid] += t;
    __syncthreads();
  }
  if (i < NN) offs[i] = sd[tid] - c;          // local exclusive
  if (tid == 255) bsum[blockIdx.x] = sd[255]; // block total
}

__global__ __launch_bounds__(256) void scan_b(
    const int* __restrict__ bsum, int* __restrict__ bbase, int* __restrict__ offs)
{
  __shared__ int sd[256];
  int tid = threadIdx.x;
  int v = (tid < SCAN_B) ? bsum[tid] : 0;
  sd[tid] = v;
  __syncthreads();
  for (int off=1; off<256; off<<=1){
    int t = (tid >= off) ? sd[tid-off] : 0;
    __syncthreads();
    sd[tid] += t;
    __syncthreads();
  }
  if (tid < SCAN_B) bbase[tid] = sd[tid] - v;
  if (tid == 255) offs[NN] = sd[255];
}

__global__ __launch_bounds__(256) void scan_c(
    const int* __restrict__ bbase, int* __restrict__ offs, int* __restrict__ curs)
{
  int i = blockIdx.x*256 + threadIdx.x;
  if (i < NN){
    int o = offs[i] + bbase[blockIdx.x];
    offs[i] = o;
    curs[i] = o;
  }
}

__global__ __launch_bounds__(256) void scatter_kernel(
    const int* __restrict__ rcv, int* __restrict__ curs, int* __restrict__ eids)
{
  int e = blockIdx.x*256 + threadIdx.x;
  if (e >= NE) return;
  int pos = atomicAdd(&curs[rcv[e]], 1);
  eids[pos] = e;
}

// ====== degree sort (per chunk), LDS-privatized counting sort ==============
// bin = NSBIN-1-min(d,NSBIN-1) => descending degree order
__global__ __launch_bounds__(256) void dhist_kernel(
    const int* __restrict__ offs, int* __restrict__ hist, int cn0, int cnn)
{
  __shared__ int lh[NSBIN];
  for (int j=threadIdx.x; j<NSBIN; j+=256) lh[j]=0;
  __syncthreads();
  int i = blockIdx.x*256 + threadIdx.x;
  if (i < cnn){
    int n = cn0 + i;
    int d = offs[n+1] - offs[n];
    int b = (d < NSBIN) ? (NSBIN-1-d) : 0;
    atomicAdd(&lh[b], 1);
  }
  __syncthreads();
  for (int j=threadIdx.x; j<NSBIN; j+=256){
    int v = lh[j];
    if (v) atomicAdd(&hist[j], v);
  }
}

__global__ __launch_bounds__(512) void dhist_scan(int* __restrict__ hist)
{
  __shared__ int sd[512];
  int t = threadIdx.x;
  int v = hist[t];
  sd[t] = v;
  __syncthreads();
  for (int off=1; off<512; off<<=1){
    int x = (t >= off) ? sd[t-off] : 0;
    __syncthreads();
    sd[t] += x;
    __syncthreads();
  }
  hist[t] = sd[t] - v;   // exclusive prefix -> global cursor
}

// per-block: LDS rank within (block,bin); ONE global atomic per (block,bin)
__global__ __launch_bounds__(256) void dsort_kernel(
    const int* __restrict__ offs, int* __restrict__ hist,
    int* __restrict__ sorted, int cn0, int cnn)
{
  __shared__ int lh[NSBIN];   // local counts
  __shared__ int lb[NSBIN];   // block base per bin
  for (int j=threadIdx.x; j<NSBIN; j+=256) lh[j]=0;
  __syncthreads();
  int i = blockIdx.x*256 + threadIdx.x;
  int b = -1, rank = 0;
  if (i < cnn){
    int n = cn0 + i;
    int d = offs[n+1] - offs[n];
    b = (d < NSBIN) ? (NSBIN-1-d) : 0;
    rank = atomicAdd(&lh[b], 1);
  }
  __syncthreads();
  for (int j=threadIdx.x; j<NSBIN; j+=256){
    int v = lh[j];
    lb[j] = v ? atomicAdd(&hist[j], v) : 0;
  }
  __syncthreads();
  if (i < cnn) sorted[cn0 + lb[b] + rank] = cn0 + i;
}

// ================= Edge+aggregate: wave per node, 2 edge-slots x 32 lanes ==
// lane = (es, l): half-wave es processes edge p0+2i+es; lane l owns m=l and
// all 8 q-components (2 SLUT float4 pairs). Epilogue: shfl_xor(32) reduce,
// half-wave writes 8 coalesced 128B stores.
// agg layout per node (c'): q0->l, q1->32+l, q2->64+l, q5->96+l,
//                           q3->128+l, q6->160+l, q4->192+l, q7->224+l
__global__ __launch_bounds__(256) void edge_agg_kernel(
    const float* __restrict__ ns, const float* __restrict__ nv,
    const float* __restrict__ sh, const float* __restrict__ nrm,
    const int* __restrict__ snd,
    const int* __restrict__ offs, const int* __restrict__ eids,
    const int* __restrict__ sorted,
    const float* __restrict__ slut,
    float* __restrict__ agg, int cn0, int cnn)
{
  int wave = threadIdx.x >> 6;
  int lane = threadIdx.x & 63;
  int es = lane >> 5;          // edge slot 0/1
  int l  = lane & 31;          // m
  int nls = blockIdx.x*4 + wave;
  if (nls >= cnn) return;
  int n = sorted[cn0 + nls];
  int p0 = offs[n], p1 = offs[n+1];
  const float4* slut4 = (const float4*)slut;
  float a0=0.f,a1=0.f,a2=0.f,a3=0.f,a4=0.f,a5=0.f,a6=0.f,a7=0.f;

  for (int base = p0; base < p1; base += 2){
    int p  = base + es;
    int pc = (p < p1) ? p : (p1 - 1);
    float ok = (p < p1) ? 1.0f : 0.0f;
    int e = eids[pc];
    int s = snd[e];
    float x = nrm[e];
    float4 y = *(const float4*)(sh + 4*e);

    float f = fminf(fmaxf(x*(float)NBINS, 0.0f), (float)NBINS - 0.001f);
    int b = (int)f;
    float tt = f - (float)b;
    const float4* Sp = slut4 + (size_t)b*64 + 2*l;
    float4 La = Sp[0];        // q0..3 @ bin
    float4 Lb = Sp[1];        // q4..7 @ bin
    float4 Lc = Sp[64];       // q0..3 @ bin+1
    float4 Ld = Sp[65];       // q4..7 @ bin+1

    float se = ns[(size_t)s*32 + l] * ok;
    const float* vp = nv + (size_t)s*96 + 3*l;
    float2 w = *(const float2*)vp;
    float v2 = vp[2];
    float v0 = w.x*ok, v1 = w.y*ok; v2 *= ok;

    float sc0 = fmaf(tt, Lc.x-La.x, La.x);
    float sc1 = fmaf(tt, Lc.y-La.y, La.y);
    float sc2 = fmaf(tt, Lc.z-La.z, La.z);
    float sc3 = fmaf(tt, Lc.w-La.w, La.w);
    float sc4 = fmaf(tt, Ld.x-Lb.x, Lb.x);
    float sc5 = fmaf(tt, Ld.y-Lb.y, Lb.y);
    float sc6 = fmaf(tt, Ld.z-Lb.z, Lb.z);
    float sc7 = fmaf(tt, Ld.w-Lb.w, Lb.w);

    float dot = fmaf(y.w, v2, fmaf(y.z, v1, y.y*v0));
    a0 = fmaf(y.x*se, sc0, a0);   // q0: y0*s
    a1 = fmaf(dot,    sc1, a1);   // q1: dot (inv_sqrt3 folded into SLUT)
    a2 = fmaf(y.x*v0, sc2, a2);   // q2: y0*v0
    a3 = fmaf(y.x*v1, sc3, a3);   // q3: y0*v1
    a4 = fmaf(y.x*v2, sc4, a4);   // q4: y0*v2
    a5 = fmaf(y.y*se, sc5, a5);   // q5: y1_0*s
    a6 = fmaf(y.z*se, sc6, a6);   // q6: y1_1*s
    a7 = fmaf(y.w*se, sc7, a7);   // q7: y1_2*s
  }

  // reduce across the two edge slots
  a0 += __shfl_xor(a0, 32); a1 += __shfl_xor(a1, 32);
  a2 += __shfl_xor(a2, 32); a3 += __shfl_xor(a3, 32);
  a4 += __shfl_xor(a4, 32); a5 += __shfl_xor(a5, 32);
  a6 += __shfl_xor(a6, 32); a7 += __shfl_xor(a7, 32);

  if (es == 0){
    int deg = p1 - p0;
    float inv = (deg > 0) ? __builtin_amdgcn_rcpf((float)deg) : 1.0f;
    float* ap = agg + (size_t)(n - cn0)*256;
    ap[l]       = a0*inv;
    ap[32+l]    = a1*inv;
    ap[64+l]    = a2*inv;
    ap[128+l]   = a3*inv;
    ap[192+l]   = a4*inv;
    ap[96+l]    = a5*inv;
    ap[160+l]   = a6*inv;
    ap[224+l]   = a7*inv;
  }
}

// ================= Node phase: no weight staging, contiguous agg slices ====
__global__ __launch_bounds__(256) __attribute__((amdgpu_waves_per_eu(3,8)))
void node_s_kernel(
    const float* __restrict__ ns, const float* __restrict__ wgt,
    const float* __restrict__ agg, int cn0, int cnn,
    float* __restrict__ out)
{
  __shared__ float red[3*64*33];     // 25.3 KB
  int lane = threadIdx.x & 63, role = threadIdx.x >> 6;
  int ro = __builtin_amdgcn_readfirstlane(role);
  int nl = blockIdx.x*64 + lane;
  bool valid = (nl < cnn);
  int nls = valid ? nl : (cnn-1);
  int n = cn0 + nl;

  float aggs[64];
  float oacc[32];
  #pragma unroll
  for (int j=0;j<32;j++) oacc[j]=0.0f;

  {
    const float4* ar = (const float4*)(agg + (size_t)nls*256);
    #pragma unroll
    for (int g=0; g<16; g++){
      float4 v = ar[g];
      aggs[4*g+0]=v.x; aggs[4*g+1]=v.y; aggs[4*g+2]=v.z; aggs[4*g+3]=v.w;
    }
  }
  const float* l1sT = wgt + RL1ST + ro*32*64;
  const float* l2s  = wgt + RL2S;
  for (int t=0;t<32;t++){
    const float4* col = (const float4*)(l1sT + t*64);
    float d0=0,d1=0,d2=0,d3=0;
    #pragma unroll
    for (int j=0;j<16;j++){
      float4 c = col[j];
      d0 = fmaf(aggs[4*j+0], c.x, d0);
      d1 = fmaf(aggs[4*j+1], c.y, d1);
      d2 = fmaf(aggs[4*j+2], c.z, d2);
      d3 = fmaf(aggs[4*j+3], c.w, d3);
    }
    float act = siluf(((d0+d1)+(d2+d3))*0.125f);
    const float4* row = (const float4*)(l2s + (size_t)(ro*32 + t)*32);
    #pragma unroll
    for (int j=0;j<8;j++){
      float4 w = row[j];
      oacc[4*j+0] = fmaf(act, w.x, oacc[4*j+0]);
      oacc[4*j+1] = fmaf(act, w.y, oacc[4*j+1]);
      oacc[4*j+2] = fmaf(act, w.z, oacc[4*j+2]);
      oacc[4*j+3] = fmaf(act, w.w, oacc[4*j+3]);
    }
  }
  {
    const float4* sp = (const float4*)(ns + (size_t)(cn0+nls)*32 + ro*8);
    #pragma unroll
    for (int q4=0;q4<2;q4++){
      float4 v = sp[q4];
      float vv[4] = {v.x, v.y, v.z, v.w};
      #pragma unroll
      for (int u=0;u<4;u++){
        int q = ro*8 + q4*4 + u;
        const float4* row = (const float4*)(l2s + (size_t)(128+q)*32);
        #pragma unroll
        for (int j=0;j<8;j++){
          float4 w = row[j];
          oacc[4*j+0] = fmaf(vv[u], w.x, oacc[4*j+0]);
          oacc[4*j+1] = fmaf(vv[u], w.y, oacc[4*j+1]);
          oacc[4*j+2] = fmaf(vv[u], w.z, oacc[4*j+2]);
          oacc[4*j+3] = fmaf(vv[u], w.w, oacc[4*j+3]);
        }
      }
    }
  }

  if (role != 0){
    float* rp = red + (role-1)*(64*33) + lane*33;
    #pragma unroll
    for (int j=0;j<32;j++) rp[j] = oacc[j];
  }
  __syncthreads();
  if (role == 0 && valid){
    #pragma unroll
    for (int j=0;j<32;j++)
      oacc[j] += red[0*(64*33)+lane*33+j] + red[1*(64*33)+lane*33+j]
               + red[2*(64*33)+lane*33+j];
    float4* op = (float4*)(out + (size_t)n*128);
    #pragma unroll
    for (int j=0;j<8;j++){
      float4 o4;
      o4.x = oacc[4*j+0]*S160; o4.y = oacc[4*j+1]*S160;
      o4.z = oacc[4*j+2]*S160; o4.w = oacc[4*j+3]*S160;
      op[j] = o4;
    }
  }
}

__global__ __launch_bounds__(192) __attribute__((amdgpu_waves_per_eu(3,8)))
void node_v_kernel(
    const float* __restrict__ nv, const float* __restrict__ wgt,
    const float* __restrict__ agg, int cn0, int cnn,
    float* __restrict__ out)
{
  __shared__ float sw[64*97];        // 24.8 KB (sgate uses first 4096 floats)
  int lane = threadIdx.x & 63, role = threadIdx.x >> 6;  // role 0..2
  int ro = __builtin_amdgcn_readfirstlane(role);
  int nl = blockIdx.x*64 + lane;
  bool valid = (nl < cnn);
  int nls = valid ? nl : (cnn-1);
  const float* arow = agg + (size_t)nls*256;

  // ---- Phase A: gates ----
  {
    float aggs[64];
    const float4* ar = (const float4*)arow;
    #pragma unroll
    for (int g=0; g<16; g++){
      float4 v = ar[g];
      aggs[4*g+0]=v.x; aggs[4*g+1]=v.y; aggs[4*g+2]=v.z; aggs[4*g+3]=v.w;
    }
    const float* l1g = wgt + RL1ST + 128*64;     // gate cols 128..191
    for (int o=ro; o<64; o+=3){
      const float4* col = (const float4*)(l1g + o*64);
      float d0=0,d1=0,d2=0,d3=0;
      #pragma unroll
      for (int j=0;j<16;j++){
        float4 c = col[j];
        d0 = fmaf(aggs[4*j+0], c.x, d0);
        d1 = fmaf(aggs[4*j+1], c.y, d1);
        d2 = fmaf(aggs[4*j+2], c.z, d2);
        d3 = fmaf(aggs[4*j+3], c.w, d3);
      }
      sw[o*64+lane] = sigf(((d0+d1)+(d2+d3))*0.125f);
    }
  }
  __syncthreads();

  // ---- Phase B: component k = role ----
  int k = role;
  float aggv[64], oacc[32];
  #pragma unroll
  for (int j=0;j<32;j++) oacc[j]=0.0f;
  {
    const float4* av = (const float4*)(arow + 64 + 64*k);
    #pragma unroll
    for (int g=0; g<16; g++){
      float4 v = av[g];
      aggv[4*g+0]=v.x; aggv[4*g+1]=v.y; aggv[4*g+2]=v.z; aggv[4*g+3]=v.w;
    }
  }
  const float* l1vT = wgt + RL1VT;
  const float* l2v  = wgt + RL2V;
  for (int o=0;o<64;o++){
    const float4* col = (const float4*)(l1vT + o*64);
    float d0=0,d1=0,d2=0,d3=0;
    #pragma unroll
    for (int j=0;j<16;j++){
      float4 c = col[j];
      d0 = fmaf(aggv[4*j+0], c.x, d0);
      d1 = fmaf(aggv[4*j+1], c.y, d1);
      d2 = fmaf(aggv[4*j+2], c.z, d2);
      d3 = fmaf(aggv[4*j+3], c.w, d3);
    }
    float gv = (((d0+d1)+(d2+d3))*0.125f) * sw[o*64+lane];
    const float4* row = (const float4*)(l2v + (size_t)o*32);
    #pragma unroll
    for (int j=0;j<8;j++){
      float4 w = row[j];
      oacc[4*j+0] = fmaf(gv, w.x, oacc[4*j+0]);
      oacc[4*j+1] = fmaf(gv, w.y, oacc[4*j+1]);
      oacc[4*j+2] = fmaf(gv, w.z, oacc[4*j+2]);
      oacc[4*j+3] = fmaf(gv, w.w, oacc[4*j+3]);
    }
  }
  {
    const float* vp = nv + (size_t)(cn0+nls)*96 + k;
    #pragma unroll 8
    for (int q=0;q<32;q++){
      float a = vp[3*q];
      const float4* row = (const float4*)(l2v + (size_t)(64+q)*32);
      #pragma unroll
      for (int j=0;j<8;j++){
        float4 w = row[j];
        oacc[4*j+0] = fmaf(a, w.x, oacc[4*j+0]);
        oacc[4*j+1] = fmaf(a, w.y, oacc[4*j+1]);
        oacc[4*j+2] = fmaf(a, w.z, oacc[4*j+2]);
        oacc[4*j+3] = fmaf(a, w.w, oacc[4*j+3]);
      }
    }
  }

  __syncthreads();          // done reading sgate region
  if (valid){
    #pragma unroll
    for (int j=0;j<32;j++) sw[lane*97 + 3*j + k] = oacc[j]*S96;
  }
  __syncthreads();
  int nb = blockIdx.x*64;
  #pragma unroll
  for (int r=0;r<8;r++){
    int F = r*192 + threadIdx.x;       // 0..1535 -> 64 nodes x 24 float4
    int i = F/24, j = F%24;
    if (nb + i < cnn){
      float4 o4;
      o4.x = sw[i*97 + 4*j + 0];
      o4.y = sw[i*97 + 4*j + 1];
      o4.z = sw[i*97 + 4*j + 2];
      o4.w = sw[i*97 + 4*j + 3];
      *(float4*)(out + (size_t)(cn0+nb+i)*128 + 32 + 4*j) = o4;
    }
  }
}

extern "C" void kernel_launch(void* const* d_in, const int* in_sizes, int n_in,
                              void* d_out, int out_size, void* d_ws, size_t ws_size,
                              hipStream_t stream) {
  const float* node_scalars = (const float*)d_in[0];
  const float* node_vectors = (const float*)d_in[1];
  const float* sh           = (const float*)d_in[2];
  const float* norm         = (const float*)d_in[3];
  const float* w1  = (const float*)d_in[4];
  const float* b1  = (const float*)d_in[5];
  const float* w2  = (const float*)d_in[6];
  const float* b2  = (const float*)d_in[7];
  const float* w3  = (const float*)d_in[8];
  const float* b3  = (const float*)d_in[9];
  const float* l1s = (const float*)d_in[10];
  const float* l1v = (const float*)d_in[11];
  const float* l2s = (const float*)d_in[12];
  const float* l2v = (const float*)d_in[13];
  const int* snd = (const int*)d_in[14];
  const int* rcv = (const int*)d_in[15];
  float* ws = (float*)d_ws;
  float* out = (float*)d_out;

  // layout: wgt | slut | ints | agg(remainder)
  size_t ws_fl = ws_size / 4;
  if (ws_fl < FIXED_FL + 64*256) return;
  size_t aggcap = (ws_fl - FIXED_FL) / 256;
  int csize = (int)((aggcap < (size_t)NN) ? aggcap : (size_t)NN);
  int nchunks = (NN + csize - 1) / csize;

  float* wgt  = ws;
  float* slut = wgt + WTOT;
  int*   ib   = (int*)(slut + SLUT_N);
  int* offs   = ib;                     // NN+1
  int* curs   = ib + NN + 1;            // NN
  int* eids   = ib + 2*NN + 1;          // NE
  int* sorted = ib + 2*NN + 1 + NE;     // NN (aliases cnt)
  int* cnt    = sorted;
  int* hist   = ib + 3*NN + 1 + NE;     // 512
  int* bsum   = hist + 512;             // 256
  int* bbase  = bsum + 256;             // 256
  float* agg  = (float*)(bbase + 256);

  hipMemsetAsync(cnt, 0, NN*sizeof(int), stream);

  convert_weights<<<(WTOT+255)/256, 256, 0, stream>>>(l1s, l1v, l2s, l2v, wgt);
  build_lut<<<NBINS+1, 128, 0, stream>>>(w1,b1,w2,b2,w3,b3, slut);

  count_kernel<<<(NE+255)/256, 256, 0, stream>>>(rcv, cnt);
  scan_a<<<SCAN_B, 256, 0, stream>>>(cnt, offs, bsum);
  scan_b<<<1, 256, 0, stream>>>(bsum, bbase, offs);
  scan_c<<<SCAN_B, 256, 0, stream>>>(bbase, offs, curs);
  scatter_kernel<<<(NE+255)/256, 256, 0, stream>>>(rcv, curs, eids);

  for (int ch = 0; ch < nchunks; ch++){
    int cn0 = ch * csize;
    int cnn = (NN - cn0 < csize) ? (NN - cn0) : csize;
    // degree-sort this chunk's nodes (descending) for balanced waves
    hipMemsetAsync(hist, 0, NSBIN*sizeof(int), stream);
    dhist_kernel<<<(cnn+255)/256, 256, 0, stream>>>(offs, hist, cn0, cnn);
    dhist_scan<<<1, 512, 0, stream>>>(hist);
    dsort_kernel<<<(cnn+255)/256, 256, 0, stream>>>(offs, hist, sorted, cn0, cnn);

    edge_agg_kernel<<<(cnn+3)/4, 256, 0, stream>>>(
        node_scalars, node_vectors, sh, norm, snd, offs, eids, sorted, slut,
        agg, cn0, cnn);
    node_s_kernel<<<(cnn+63)/64, 256, 0, stream>>>(
        node_scalars, wgt, agg, cn0, cnn, out);
    node_v_kernel<<<(cnn+63)/64, 192, 0, stream>>>(
        node_vectors, wgt, agg, cn0, cnn, out);
  }
}